// Round 16
// baseline (131.419 us; speedup 1.0000x reference)
//
#include <hip/hip_runtime.h>
#include <cstdint>

// ---------------------------------------------------------------------------
// GRUCell w/ BatchNorm on input projection.  B=4096, I=H=1024, 3H=3072.
// Reference:  c = tanh(c_bn + (r * hx) @ c_h)  (Python left-assoc * then @).
// fp16 scheme (mfma_f32_16x16x32_f16, fp32 accum):
//   MEGA8: uniform 1-pass 4096x6144 GEMM, 256x256 tiles, 8-phase counted-
//     vmcnt schedule (T3+T4+T5), 384 blocks x 512 thr, 128KB LDS, 1 blk/CU.
//     cols: [g 0..3071 | gh_u 3072..4095 | ghr_hi 4096..5119 | ghr_lo 5120..]
//   bn_final -> scale/shift;  rx = sigmoid(BN(g_r)+hi+lo)*hx  (fp16)
//   GEMM3: ch = rx @ wh_c, 64x64 BK=128, 1024 blocks; epilogue u+hy.
// Ledger (per tile t, phases q0..q3): stage q0:(t+1)Akh1 q1:(t+1)Bkh1
//   q2:(t+2)Akh0 q3:(t+2)Bkh0; vmcnt(6) before q1/q3 trailing barriers.
//   kh0 halves dead after q1, kh1 after q3 -> no stage clobbers live data.
// ---------------------------------------------------------------------------

typedef float    f4    __attribute__((ext_vector_type(4)));
typedef _Float16 half4 __attribute__((ext_vector_type(4)));
typedef _Float16 half8 __attribute__((ext_vector_type(8)));
typedef float    f32x4 __attribute__((ext_vector_type(4)));

#define SBAR __builtin_amdgcn_sched_barrier(0)

__device__ __forceinline__ float sigm(float x) { return 1.f / (1.f + __expf(-x)); }
__device__ __forceinline__ float tanh_sat(float t) {
  return 1.f - 2.f / (__expf(2.f * t) + 1.f);   // saturates correctly for big t
}

// async global->LDS DMA, 16B/lane: LDS dst = wave-uniform base + lane*16
__device__ __forceinline__ void gload16(const _Float16* g, _Float16* l) {
  __builtin_amdgcn_global_load_lds(
      (const __attribute__((address_space(1))) void*)g,
      (__attribute__((address_space(3))) void*)l, 16, 0, 0);
}

// --------------------------- prep (one dispatch) ----------------------------

__global__ void prep_all(const float* __restrict__ input, const float* __restrict__ hx,
                         const float* __restrict__ wi, const float* __restrict__ wh,
                         _Float16* __restrict__ Xf16, _Float16* __restrict__ Hf16,
                         _Float16* __restrict__ WiT, _Float16* __restrict__ WhTh,
                         _Float16* __restrict__ WhTl) {
  constexpr int N4 = 4096 * 1024 / 4;   // float4s per input array = 1048576
  __shared__ float sh[32][33];
  int bid = blockIdx.x;
  if (bid < 8192) {                     // 8192*256 = 2*N4 threads exactly
    int i = bid * 256 + threadIdx.x;
    const float* s;
    _Float16* d;
    if (i < N4) { s = input; d = Xf16; }
    else        { s = hx;    d = Hf16; i -= N4; }
    f4 v = ((const f4*)s)[i];
    half4 h;
#pragma unroll
    for (int j = 0; j < 4; ++j) h[j] = (_Float16)v[j];
    ((half4*)d)[i] = h;
    return;
  }
  int b2 = bid - 8192;                  // 0..6143: [z][ky 0..31][nx 0..95]
  int z = b2 / 3072; b2 %= 3072;
  int nx = b2 % 96, ky = b2 / 96;
  const float* W = z ? wh : wi;
  int n0 = nx * 32, k0 = ky * 32;
  int tx = threadIdx.x & 31, ty = threadIdx.x >> 5;  // ty 0..7
#pragma unroll
  for (int i = 0; i < 4; ++i) {
    int k = ty + i * 8;
    sh[k][tx] = W[(size_t)(k0 + k) * 3072 + n0 + tx];
  }
  __syncthreads();
  const bool wlo = z && n0 >= 1024 && n0 < 2048;     // r-cols need lo part
#pragma unroll
  for (int i = 0; i < 4; ++i) {
    int nn = ty + i * 8;
    float v = sh[tx][nn];                      // = W[k0+tx][n0+nn]
    size_t o = (size_t)(n0 + nn) * 1024 + k0 + tx;
    _Float16 h = (_Float16)v;
    if (!z) {
      WiT[o] = h;
    } else {
      WhTh[o] = h;
      if (wlo) WhTl[o] = (_Float16)(v - (float)h);
    }
  }
}

// ---------------- MEGA8: 256x256 tiles, 8-phase counted-vmcnt ----------------
// 8 waves (2M x 4N): wave (wr,wc) owns rows wr*128+0..127, cols wc*64+0..63.
// LDS per buffer: A_kh0 | A_kh1 | B_kh0 | B_kh1 (each 256 rows x 32 k-elems =
// 16KB).  Slot swizzle: LDS (r, s) holds k-slot s ^ (r&3) ^ ((r>>2)&3)
// (involution; conflict-free per 8-lane group on ds_read_b128; linear dest
// for global_load_lds with inverse-swizzled per-lane global source).

__global__ __launch_bounds__(512, 2) void gemm_mega8(
    const _Float16* __restrict__ Xf16, const _Float16* __restrict__ Hf16,
    const _Float16* __restrict__ WiT, const _Float16* __restrict__ WhTh,
    const _Float16* __restrict__ WhTl, _Float16* __restrict__ g16,
    _Float16* __restrict__ ghbuf, float* __restrict__ psum,
    float* __restrict__ psq) {
  __shared__ _Float16 lds[65536];       // 128 KiB = 2 buf x 4 halves x 16KB

  const int tid  = threadIdx.x;
  const int lane = tid & 63;
  const int wid  = tid >> 6;            // 0..7
  const int wr   = wid >> 2;            // 0..1
  const int wc   = wid & 3;             // 0..3

  // 384 blocks = 24 bx x 16 by; XCD 2D (4 colgrp x 2 rowgrp)
  int bid = blockIdx.x;
  int xcd = bid & 7, ii = bid >> 3;     // ii 0..47
  int bx  = (xcd & 3) * 6 + ii % 6;     // 0..23
  int by  = (xcd >> 2) * 8 + ii / 6;    // 0..15
  const int brow = by * 256;
  const int bcol = bx * 256;            // 0..6143

  const _Float16* A;
  const _Float16* Bp;
  if (bcol < 3072)      { A = Xf16; Bp = WiT  + (size_t)bcol * 1024; }
  else if (bcol < 5120) { A = Hf16; Bp = WhTh + (size_t)(bcol - 3072) * 1024; }
  else                  { A = Hf16; Bp = WhTl + (size_t)(bcol - 4096) * 1024; }
  A += (size_t)brow * 1024;

  // staging geometry: half = 16 chunks of 1KB; wave stages chunks wid*2, +1.
  const int sks = (lane & 3) ^ ((lane >> 2) & 3) ^ (lane >> 4);  // src k-slot
  const int c0 = wid * 2, c1 = c0 + 1;
  const int sr0 = c0 * 16 + (lane >> 2);
  const int sr1 = c1 * 16 + (lane >> 2);

  auto stage = [&](const _Float16* P, int k0h, int hoff) {
    gload16(P + (size_t)sr0 * 1024 + k0h + sks * 8, lds + hoff + c0 * 512);
    gload16(P + (size_t)sr1 * 1024 + k0h + sks * 8, lds + hoff + c1 * 512);
  };

  // fragment-read geometry (slot is lane-only for our row bases)
  const int rslot = (((lane >> 4) ^ (lane & 3) ^ ((lane >> 2) & 3)) << 3);
  const int arow  = wr * 128 + (lane & 15);
  const int brow2 = wc * 64 + (lane & 15);

  f32x4 acc[8][4];
#pragma unroll
  for (int m = 0; m < 8; ++m)
#pragma unroll
    for (int n = 0; n < 4; ++n) acc[m][n] = f32x4{0.f, 0.f, 0.f, 0.f};

  auto rdA = [&](int buf, int h, int mh, half8* a) {
    const int base = buf + h * 8192;
#pragma unroll
    for (int m = 0; m < 4; ++m) {
      int r = arow + (mh * 4 + m) * 16;
      a[m] = *(const half8*)(lds + base + r * 32 + rslot);
    }
  };
  auto rdB = [&](int buf, int h, half8* b) {
    const int base = buf + 16384 + h * 8192;
#pragma unroll
    for (int n = 0; n < 4; ++n) {
      int r = brow2 + n * 16;
      b[n] = *(const half8*)(lds + base + r * 32 + rslot);
    }
  };
  auto mma = [&](half8* a, half8* b, int mh) {
    __builtin_amdgcn_s_setprio(1);
#pragma unroll
    for (int m = 0; m < 4; ++m)
#pragma unroll
      for (int n = 0; n < 4; ++n)
        acc[mh * 4 + m][n] = __builtin_amdgcn_mfma_f32_16x16x32_f16(
            a[m], b[n], acc[mh * 4 + m][n], 0, 0, 0);
    __builtin_amdgcn_s_setprio(0);
  };

  // ---- prologue: t0 all 4 halves + t1 kh0 halves (12 loads/wave)
  stage(A,  0, 0);                 // t0 A kh0
  stage(Bp, 0, 16384);             // t0 B kh0
  stage(A,  32, 8192);             // t0 A kh1
  stage(Bp, 32, 24576);            // t0 B kh1
  stage(A,  64, 32768);            // t1 A kh0
  stage(Bp, 64, 32768 + 16384);    // t1 B kh0
  SBAR;
  asm volatile("s_waitcnt vmcnt(8)" ::: "memory");   // t0 kh0 landed
  SBAR;
  __builtin_amdgcn_s_barrier();
  SBAR;

  // ---- main loop: 16 K-tiles, 4 phases each
  for (int t = 0; t < 16; ++t) {
    const int buf  = (t & 1) << 15;       // tile t's buffer (elem offset)
    const int nbuf = buf ^ 32768;         // tile t+1's buffer
    const bool s01 = t <= 14;             // stage (t+1) kh1 halves
    const bool s23 = t <= 13;             // stage (t+2) kh0 halves
    half8 a[4], b[4];

    // -- q0: h0, m0-3
    rdA(buf, 0, 0, a);
    rdB(buf, 0, b);
    if (s01) stage(A, (t + 1) * 64 + 32, nbuf + 8192);
    SBAR; __builtin_amdgcn_s_barrier(); SBAR;
    mma(a, b, 0);
    SBAR; __builtin_amdgcn_s_barrier(); SBAR;

    // -- q1: h0, m4-7
    rdA(buf, 0, 1, a);
    if (s01) stage(Bp, (t + 1) * 64 + 32, nbuf + 24576);
    SBAR; __builtin_amdgcn_s_barrier(); SBAR;
    mma(a, b, 1);
    if (s01) { SBAR; asm volatile("s_waitcnt vmcnt(6)" ::: "memory"); }
    SBAR; __builtin_amdgcn_s_barrier(); SBAR;

    // -- q2: h1, m0-3
    rdA(buf, 1, 0, a);
    rdB(buf, 1, b);
    if (s23) stage(A, (t + 2) * 64, buf);
    SBAR; __builtin_amdgcn_s_barrier(); SBAR;
    mma(a, b, 0);
    SBAR; __builtin_amdgcn_s_barrier(); SBAR;

    // -- q3: h1, m4-7
    rdA(buf, 1, 1, a);
    if (s23) stage(Bp, (t + 2) * 64, buf + 16384);
    SBAR; __builtin_amdgcn_s_barrier(); SBAR;
    mma(a, b, 1);
    if (s23)          { SBAR; asm volatile("s_waitcnt vmcnt(6)" ::: "memory"); }
    else if (t == 14) { SBAR; asm volatile("s_waitcnt vmcnt(0)" ::: "memory"); }
    SBAR; __builtin_amdgcn_s_barrier(); SBAR;
  }

  // ---- epilogue.  D(row,col): col = lane&15, row = (lane>>4)*4 + j.
  if (bcol < 3072) {                  // g (fp16) + BN column partial sums
    float s[4] = {0.f, 0.f, 0.f, 0.f}, q[4] = {0.f, 0.f, 0.f, 0.f};
#pragma unroll
    for (int m = 0; m < 8; ++m) {
      int row = brow + wr * 128 + m * 16 + (lane >> 4) * 4;
#pragma unroll
      for (int n = 0; n < 4; ++n) {
        int gcol = bcol + wc * 64 + n * 16 + (lane & 15);
#pragma unroll
        for (int j = 0; j < 4; ++j) {
          float v = acc[m][n][j];
          g16[(size_t)(row + j) * 3072 + gcol] = (_Float16)v;
          s[n] += v;
          q[n] += v * v;
        }
      }
    }
#pragma unroll
    for (int n = 0; n < 4; ++n) {
      float sv = s[n], qv = q[n];
      sv += __shfl_xor(sv, 16); sv += __shfl_xor(sv, 32);
      qv += __shfl_xor(qv, 16); qv += __shfl_xor(qv, 32);
      if (lane < 16) {
        int prow = by * 2 + wr;                       // 32 partial rows
        int pcol = bcol + wc * 64 + n * 16 + lane;
        psum[(size_t)prow * 3072 + pcol] = sv;
        psq [(size_t)prow * 3072 + pcol] = qv;
      }
    }
  } else {                            // raw gh (fp16), ghbuf stride 3072
    int gc0 = bcol - 3072;
#pragma unroll
    for (int m = 0; m < 8; ++m) {
      int row = brow + wr * 128 + m * 16 + (lane >> 4) * 4;
#pragma unroll
      for (int n = 0; n < 4; ++n) {
        int gcol = gc0 + wc * 64 + n * 16 + (lane & 15);
#pragma unroll
        for (int j = 0; j < 4; ++j)
          ghbuf[(size_t)(row + j) * 3072 + gcol] = (_Float16)acc[m][n][j];
      }
    }
  }
}

// ------------------------------- GEMM core (small) ---------------------------
// 2-barrier gload_lds kloop for gemm_last (64-k rows, XOR row&7 swizzle).

template <bool LO, int BMt, int BNt, int BKt>
__device__ __forceinline__ void kloop(
    const _Float16* __restrict__ A, const _Float16* __restrict__ Bh,
    const _Float16* __restrict__ Bl, _Float16* lds, int tid,
    f32x4 (&acc)[BMt / 32][BNt / 32]) {
  constexpr int TA = BMt * BKt, TB = BNt * BKt;
  constexpr int MF = BMt / 32, WC = BNt / 32;
  constexpr int NT = 1024 / BKt;
  constexpr int RPC = 512 / BKt;          // rows per 1KB staging chunk
  constexpr int SLOTS = BKt / 8;          // 16B k-groups per row
  constexpr int AW = TA / 512 / 4;        // A chunks per wave
  constexpr int BW = TB / 512 / 4;        // B chunks per wave
  const int lane = tid & 63, wid = tid >> 6;
  const int srow  = lane / SLOTS;
  const int sslot = lane % SLOTS;
  const int wrow = (wid >> 1) * (BMt / 2);
  const int wcol = (wid & 1) * (BNt / 2);

  for (int kt = 0; kt < NT; ++kt) {
    const int k0 = kt * BKt;
    __syncthreads();
#pragma unroll
    for (int i = 0; i < AW; ++i) {
      int c = wid * AW + i;
      int rg = c * RPC + srow;
      gload16(A + (size_t)rg * 1024 + k0 + ((sslot ^ (rg & 7)) << 3),
              lds + c * 512);
    }
#pragma unroll
    for (int i = 0; i < BW; ++i) {
      int c = wid * BW + i;
      int rg = c * RPC + srow;
      size_t go = (size_t)rg * 1024 + k0 + ((sslot ^ (rg & 7)) << 3);
      gload16(Bh + go, lds + TA + c * 512);
      if constexpr (LO) gload16(Bl + go, lds + TA + TB + c * 512);
    }
    __syncthreads();

#pragma unroll
    for (int h = 0; h < BKt / 32; ++h) {
      half8 a[MF], bhv[WC], blv[WC];
      const int kg = h * 4 + (lane >> 4);
#pragma unroll
      for (int m = 0; m < MF; ++m) {
        int r = wrow + m * 16 + (lane & 15);
        a[m] = *(const half8*)(lds + r * BKt + ((kg ^ (r & 7)) << 3));
      }
#pragma unroll
      for (int n = 0; n < WC; ++n) {
        int r = wcol + n * 16 + (lane & 15);
        int off = TA + r * BKt + ((kg ^ (r & 7)) << 3);
        bhv[n] = *(const half8*)(lds + off);
        if constexpr (LO) blv[n] = *(const half8*)(lds + TB + off);
      }
#pragma unroll
      for (int m = 0; m < MF; ++m)
#pragma unroll
        for (int n = 0; n < WC; ++n) {
          acc[m][n] = __builtin_amdgcn_mfma_f32_16x16x32_f16(
              a[m], bhv[n], acc[m][n], 0, 0, 0);
          if constexpr (LO)
            acc[m][n] = __builtin_amdgcn_mfma_f32_16x16x32_f16(
                a[m], blv[n], acc[m][n], 0, 0, 0);
        }
    }
  }
}

// ---- GEMM3: ch = rx @ wh_c (64x64 tiles, BK=128, 1024 blocks);
//      epilogue computes u (from raw gh_u) and hy.  XCD = 2 colgrp x 4 rowgrp.
__global__ __launch_bounds__(256, 4) void gemm_last(
    const _Float16* __restrict__ RXf16, const _Float16* __restrict__ Bc,
    const _Float16* __restrict__ g16, const _Float16* __restrict__ ghbuf,
    const _Float16* __restrict__ Hf16, const float* __restrict__ scale,
    const float* __restrict__ shift, float* __restrict__ out) {
  __shared__ _Float16 lds[64 * 128 + 64 * 128];      // 32 KiB

  const int tid  = threadIdx.x;
  const int lane = tid & 63;
  const int wid  = tid >> 6;

  int bid = blockIdx.x;                              // 0..1023
  int xcd = bid & 7;
  int i   = bid >> 3;                                // 0..127
  int bx  = (xcd & 1) * 8 + (i & 7);                 // 0..15
  int by  = (xcd >> 1) * 16 + (i >> 3);              // 0..63

  const int brow = by * 64;
  const int bcol = bx * 64;                          // 0..1023
  const int wrow = (wid >> 1) * 32;
  const int wcol = (wid & 1) * 32;

  f32x4 acc[2][2];
#pragma unroll
  for (int a = 0; a < 2; ++a)
#pragma unroll
    for (int j = 0; j < 2; ++j) acc[a][j] = f32x4{0.f, 0.f, 0.f, 0.f};

  kloop<false, 64, 64, 128>(RXf16 + (size_t)brow * 1024,
                            Bc + (size_t)bcol * 1024, nullptr, lds, tid, acc);

#pragma unroll
  for (int m = 0; m < 2; ++m) {
    int row0 = brow + wrow + m * 16 + (lane >> 4) * 4;
#pragma unroll
    for (int n = 0; n < 2; ++n) {
      int lcol = bcol + wcol + n * 16 + (lane & 15);
      float sc_u = scale[lcol],        sf_u = shift[lcol];
      float sc_c = scale[2048 + lcol], sf_c = shift[2048 + lcol];
#pragma unroll
      for (int j = 0; j < 4; ++j) {
        int row = row0 + j;
        float gu = (float)g16[(size_t)row * 3072 + lcol];
        float hu = (float)ghbuf[(size_t)row * 3072 + lcol];
        float u  = sigm(gu * sc_u + sf_u + hu);
        float gc = (float)g16[(size_t)row * 3072 + 2048 + lcol];
        float c  = tanh_sat(gc * sc_c + sf_c + acc[m][n][j]);
        float x  = (float)Hf16[(size_t)row * 1024 + lcol];
        out[(size_t)row * 1024 + lcol] = x + u * (c - x);
      }
    }
  }
}

// --------------------------- BN final ---------------------------------------

__global__ void bn_final(const float* __restrict__ psum, const float* __restrict__ psq,
                         const float* __restrict__ gamma, const float* __restrict__ beta,
                         const float* __restrict__ bias, float* __restrict__ scale,
                         float* __restrict__ shift, int nparts, int Ncols, float invM) {
  int col = blockIdx.x * blockDim.x + threadIdx.x;
  if (col >= Ncols) return;
  float s = 0.f, q = 0.f;
  for (int i = 0; i < nparts; ++i) {
    s += psum[(size_t)i * Ncols + col];
    q += psq [(size_t)i * Ncols + col];
  }
  float m   = s * invM;
  float var = q * invM - m * m;
  float r   = rsqrtf(var + 1e-5f);
  float sc  = r * gamma[col];
  scale[col] = sc;
  shift[col] = beta[col] + bias[col] - m * sc;
}

// ------------- rx = sigmoid(BN(g_r) + ghr_hi + ghr_lo) * hx -----------------

__global__ void rx_split(const _Float16* __restrict__ g16,
                         const _Float16* __restrict__ ghbuf,
                         const _Float16* __restrict__ Hf16,
                         const float* __restrict__ scale,
                         const float* __restrict__ shift,
                         _Float16* __restrict__ rx) {
  int idx = blockIdx.x * blockDim.x + threadIdx.x;   // 4096*256
  int row = idx >> 8;
  int cv  = idx & 255;
  half4 gr  = ((const half4*)g16)[(size_t)row * 768 + 256 + cv];   // g r-cols
  half4 hrh = ((const half4*)ghbuf)[(size_t)row * 768 + 256 + cv]; // hi part
  half4 hrl = ((const half4*)ghbuf)[(size_t)row * 768 + 512 + cv]; // lo part
  half4 xv  = ((const half4*)Hf16)[(size_t)row * 256 + cv];
  int col = 1024 + cv * 4;
  f4 sr = *(const f4*)&scale[col];
  f4 fr = *(const f4*)&shift[col];
  half4 o;
#pragma unroll
  for (int j = 0; j < 4; ++j) {
    float hr = (float)hrh[j] + (float)hrl[j];
    float r = sigm((float)gr[j] * sr[j] + fr[j] + hr);
    o[j] = (_Float16)(r * (float)xv[j]);
  }
  ((half4*)rx)[(size_t)row * 256 + cv] = o;
}

// ------------------------------ launch ---------------------------------------

extern "C" void kernel_launch(void* const* d_in, const int* in_sizes, int n_in,
                              void* d_out, int out_size, void* d_ws, size_t ws_size,
                              hipStream_t stream) {
  const float* input = (const float*)d_in[0];   // 4096x1024
  const float* hx    = (const float*)d_in[1];   // 4096x1024
  const float* wi    = (const float*)d_in[2];   // 1024x3072
  const float* wh    = (const float*)d_in[3];   // 1024x3072
  const float* bias  = (const float*)d_in[4];   // 3072
  const float* gamma = (const float*)d_in[5];   // 3072
  const float* beta  = (const float*)d_in[6];   // 3072
  float* out = (float*)d_out;

  const int B = 4096, N3 = 3072;

  char* ws = (char*)d_ws;
  _Float16* g16   = (_Float16*)(ws);               // 24 MiB [4096][3072]
  _Float16* ghbuf = (_Float16*)(ws + 25165824);    // 24 MiB [4096][3072]
  _Float16* Xf16  = (_Float16*)(ws + 50331648);    // 8 MiB
  _Float16* Hf16  = (_Float16*)(ws + 58720256);    // 8 MiB
  _Float16* RXf16 = (_Float16*)(ws + 67108864);    // 8 MiB
  _Float16* WiT   = (_Float16*)(ws + 75497472);    // 6 MiB
  _Float16* WhTh  = (_Float16*)(ws + 81788928);    // 6 MiB
  _Float16* WhTl  = (_Float16*)(ws + 88080384);    // 6 MiB (r-cols only)
  float*    psum  = (float*)   (ws + 94371840);    // 384 KiB [32][3072]
  float*    psq   = (float*)   (ws + 94765056);    // 384 KiB
  float*    scale = (float*)   (ws + 95158272);    // 12 KiB
  float*    shift = (float*)   (ws + 95170560);    // 12 KiB

  // ---- prep: converts + transposes, one dispatch
  prep_all<<<8192 + 6144, 256, 0, stream>>>(input, hx, wi, wh,
                                            Xf16, Hf16, WiT, WhTh, WhTl);

  // ---- MEGA8: [g | gh_u | ghr_hi | ghr_lo] 256x256 8-phase, 384 blocks
  gemm_mega8<<<384, 512, 0, stream>>>(
      Xf16, Hf16, WiT, WhTh, WhTl, g16, ghbuf, psum, psq);

  // ---- BN fold (32 partial rows now)
  bn_final<<<12, 256, 0, stream>>>(psum, psq, gamma, beta, bias,
                                   scale, shift, 32, N3, 1.f / (float)B);

  // ---- rx = sigmoid(BN(g_r) + hi + lo) * hx
  rx_split<<<4096, 256, 0, stream>>>(g16, ghbuf, Hf16, scale, shift, RXf16);

  // ---- GEMM3 + fused u/c/hy epilogue (64x64, BK=128, 1024 blocks)
  gemm_last<<<1024, 256, 0, stream>>>(
      RXf16, WhTh + (size_t)2048 * 1024, g16, ghbuf, Hf16, scale, shift, out);
}

// Round 17
// 116.569 us; speedup vs baseline: 1.1274x; 1.1274x over previous
//
#include <hip/hip_runtime.h>
#include <cstdint>

// ---------------------------------------------------------------------------
// GRUCell w/ BatchNorm on input projection.  B=4096, I=H=1024, 3H=3072.
// Reference:  c = tanh(c_bn + (r * hx) @ c_h)  (Python left-assoc * then @).
// fp16 scheme (mfma_f32_16x16x32_f16, fp32 accum):
//   MEGA (one dispatch, 1536 blocks, 32KB LDS both phases):
//     blocks 0..1023 : 128x128 1-pass over [g(3072c) | gh_u(1024c)]
//     blocks 1024..1535: 128x64 2-pass (B hi+lo) over gh_r(1024c)
//   bn_final -> scale/shift;  rx = sigmoid(BN(g_r)+gh_r)*hx  (fp16)
//   GEMM3: ch = rx @ wh_c, 64x64 tiles BK=128, 1024 blocks; epilogue u+hy.
// Lessons: blocks/CU >= 4 beats tile density (r5/r11); BK depth is the safe
// density lever (r12); NO reg round-trip in mega staging (r6/r13); 2D XCD
// tiling cuts FETCH 78.6->50.5MB (r15) but mega is stall-bound (time flat);
// 8-phase 256^2 port (r16) regressed 69->95us (grid quantization 1.5 rounds
// + 4.7M bank conflicts + schedule mismatch) -> reverted to this r15 config.
// ---------------------------------------------------------------------------

typedef float    f4    __attribute__((ext_vector_type(4)));
typedef _Float16 half4 __attribute__((ext_vector_type(4)));
typedef _Float16 half8 __attribute__((ext_vector_type(8)));
typedef float    f32x4 __attribute__((ext_vector_type(4)));

__device__ __forceinline__ float sigm(float x) { return 1.f / (1.f + __expf(-x)); }
__device__ __forceinline__ float tanh_sat(float t) {
  return 1.f - 2.f / (__expf(2.f * t) + 1.f);   // saturates correctly for big t
}

// async global->LDS DMA, 16B/lane: LDS dst = wave-uniform base + lane*16
__device__ __forceinline__ void gload16(const _Float16* g, _Float16* l) {
  __builtin_amdgcn_global_load_lds(
      (const __attribute__((address_space(1))) void*)g,
      (__attribute__((address_space(3))) void*)l, 16, 0, 0);
}

// --------------------------- prep (one dispatch) ----------------------------
// bid < 8192: f32->fp16 convert of input+hx (x4 vectorized; 2*1048576 float4s).
// bid >= 8192: 32x32 transpose tiles; z=0 -> wi->WiT; z=1 -> wh->WhTh(+lo r).

__global__ void prep_all(const float* __restrict__ input, const float* __restrict__ hx,
                         const float* __restrict__ wi, const float* __restrict__ wh,
                         _Float16* __restrict__ Xf16, _Float16* __restrict__ Hf16,
                         _Float16* __restrict__ WiT, _Float16* __restrict__ WhTh,
                         _Float16* __restrict__ WhTl) {
  constexpr int N4 = 4096 * 1024 / 4;   // float4s per input array = 1048576
  __shared__ float sh[32][33];
  int bid = blockIdx.x;
  if (bid < 8192) {                     // 8192*256 = 2*N4 threads exactly
    int i = bid * 256 + threadIdx.x;
    const float* s;
    _Float16* d;
    if (i < N4) { s = input; d = Xf16; }
    else        { s = hx;    d = Hf16; i -= N4; }
    f4 v = ((const f4*)s)[i];
    half4 h;
#pragma unroll
    for (int j = 0; j < 4; ++j) h[j] = (_Float16)v[j];
    ((half4*)d)[i] = h;
    return;
  }
  int b2 = bid - 8192;                  // 0..6143: [z][ky 0..31][nx 0..95]
  int z = b2 / 3072; b2 %= 3072;
  int nx = b2 % 96, ky = b2 / 96;
  const float* W = z ? wh : wi;
  int n0 = nx * 32, k0 = ky * 32;
  int tx = threadIdx.x & 31, ty = threadIdx.x >> 5;  // ty 0..7
#pragma unroll
  for (int i = 0; i < 4; ++i) {
    int k = ty + i * 8;
    sh[k][tx] = W[(size_t)(k0 + k) * 3072 + n0 + tx];
  }
  __syncthreads();
  const bool wlo = z && n0 >= 1024 && n0 < 2048;     // r-cols need lo part
#pragma unroll
  for (int i = 0; i < 4; ++i) {
    int nn = ty + i * 8;
    float v = sh[tx][nn];                      // = W[k0+tx][n0+nn]
    size_t o = (size_t)(n0 + nn) * 1024 + k0 + tx;
    _Float16 h = (_Float16)v;
    if (!z) {
      WiT[o] = h;
    } else {
      WhTh[o] = h;
      if (wlo) WhTl[o] = (_Float16)(v - (float)h);
    }
  }
}

// ------------------------------- GEMM core ----------------------------------
// BMt x BNt tile, BKt in {64,128}, 4 waves (2x2).  LDS [rows][BKt/8 slots of
// 8 fp16]; linear slot holds k-group (slot ^ (row&7)): inverse-swizzled
// global source for global_load_lds (dest linear) + same XOR on ds_read.
// K-loop: barrier; stage-DMA(kt); barrier; compute(kt).

template <bool LO, int BMt, int BNt, int BKt>
__device__ __forceinline__ void kloop(
    const _Float16* __restrict__ A, const _Float16* __restrict__ Bh,
    const _Float16* __restrict__ Bl, _Float16* lds, int tid,
    f32x4 (&acc)[BMt / 32][BNt / 32]) {
  constexpr int TA = BMt * BKt, TB = BNt * BKt;
  constexpr int MF = BMt / 32, WC = BNt / 32;
  constexpr int NT = 1024 / BKt;
  constexpr int RPC = 512 / BKt;          // rows per 1KB staging chunk
  constexpr int SLOTS = BKt / 8;          // 16B k-groups per row
  constexpr int AW = TA / 512 / 4;        // A chunks per wave
  constexpr int BW = TB / 512 / 4;        // B chunks per wave
  const int lane = tid & 63, wid = tid >> 6;
  const int srow  = lane / SLOTS;         // row within chunk
  const int sslot = lane % SLOTS;
  const int wrow = (wid >> 1) * (BMt / 2);
  const int wcol = (wid & 1) * (BNt / 2);

  for (int kt = 0; kt < NT; ++kt) {
    const int k0 = kt * BKt;
    __syncthreads();                  // all waves done reading prev tile
#pragma unroll
    for (int i = 0; i < AW; ++i) {
      int c = wid * AW + i;
      int rg = c * RPC + srow;
      gload16(A + (size_t)rg * 1024 + k0 + ((sslot ^ (rg & 7)) << 3),
              lds + c * 512);
    }
#pragma unroll
    for (int i = 0; i < BW; ++i) {
      int c = wid * BW + i;
      int rg = c * RPC + srow;
      size_t go = (size_t)rg * 1024 + k0 + ((sslot ^ (rg & 7)) << 3);
      gload16(Bh + go, lds + TA + c * 512);
      if constexpr (LO) gload16(Bl + go, lds + TA + TB + c * 512);
    }
    __syncthreads();                  // drains vmcnt(0) -> LDS valid

#pragma unroll
    for (int h = 0; h < BKt / 32; ++h) {
      half8 a[MF], bhv[WC], blv[WC];
      const int kg = h * 4 + (lane >> 4);
#pragma unroll
      for (int m = 0; m < MF; ++m) {
        int r = wrow + m * 16 + (lane & 15);
        a[m] = *(const half8*)(lds + r * BKt + ((kg ^ (r & 7)) << 3));
      }
#pragma unroll
      for (int n = 0; n < WC; ++n) {
        int r = wcol + n * 16 + (lane & 15);
        int off = TA + r * BKt + ((kg ^ (r & 7)) << 3);
        bhv[n] = *(const half8*)(lds + off);
        if constexpr (LO) blv[n] = *(const half8*)(lds + TB + off);
      }
#pragma unroll
      for (int m = 0; m < MF; ++m)
#pragma unroll
        for (int n = 0; n < WC; ++n) {
          acc[m][n] = __builtin_amdgcn_mfma_f32_16x16x32_f16(
              a[m], bhv[n], acc[m][n], 0, 0, 0);
          if constexpr (LO)
            acc[m][n] = __builtin_amdgcn_mfma_f32_16x16x32_f16(
                a[m], blv[n], acc[m][n], 0, 0, 0);
        }
    }
  }
}

// ---- MEGA: 1536 blocks.  0..1023: 128x128 1-pass over [g | gh_u] (4096c).
//                          1024..1535: 128x64 2-pass over gh_r (1024c).
// 2D XCD tiling: phase-1 XCD = (colgrp = xcd&3 of 8 panels, rowgrp = xcd>>2
// of 16 stripes); bx fastest within XCD so resident blocks share the A
// stripe and the 8 B panels stay L2-resident.
__global__ __launch_bounds__(256, 4) void gemm_mega(
    const _Float16* __restrict__ Xf16, const _Float16* __restrict__ Hf16,
    const _Float16* __restrict__ WiT, const _Float16* __restrict__ WhTh,
    const _Float16* __restrict__ WhTl, _Float16* __restrict__ g16,
    _Float16* __restrict__ ghbuf, float* __restrict__ psum,
    float* __restrict__ psq) {
  __shared__ _Float16 lds[16384];                    // 32 KiB both phases

  const int tid  = threadIdx.x;
  const int lane = tid & 63;
  const int wid  = tid >> 6;
  const int bid  = blockIdx.x;

  if (bid < 1024) {
    // ---- phase 1: 128x128, 1-pass.  XCD = 4 colgrp x 2 rowgrp; bx fast.
    int xcd = bid & 7;
    int i   = bid >> 3;                              // 0..127
    int bx  = (xcd & 3) * 8 + (i & 7);               // 0..31
    int by  = (xcd >> 2) * 16 + (i >> 3);            // 0..31
    const int brow = by * 128;
    const int bcol = bx * 128;                       // 0..4095
    const bool is_g = bcol < 3072;
    const int wrow = (wid >> 1) * 64;
    const int wcol = (wid & 1) * 64;

    const _Float16* Ap = (is_g ? Xf16 : Hf16) + (size_t)brow * 1024;
    const _Float16* Bp = is_g ? WiT + (size_t)bcol * 1024
                              : WhTh + (size_t)(bcol - 3072) * 1024;

    f32x4 acc[4][4];
#pragma unroll
    for (int a = 0; a < 4; ++a)
#pragma unroll
      for (int j = 0; j < 4; ++j) acc[a][j] = f32x4{0.f, 0.f, 0.f, 0.f};

    kloop<false, 128, 128, 64>(Ap, Bp, nullptr, lds, tid, acc);

    // D(row,col): col = lane&15, row = (lane>>4)*4 + j
    if (is_g) {                       // g (fp16) + BN column partial sums
      float s[4] = {0.f, 0.f, 0.f, 0.f}, q[4] = {0.f, 0.f, 0.f, 0.f};
#pragma unroll
      for (int m = 0; m < 4; ++m) {
        int row = brow + wrow + m * 16 + (lane >> 4) * 4;
#pragma unroll
        for (int n = 0; n < 4; ++n) {
          int gcol = bcol + wcol + n * 16 + (lane & 15);
#pragma unroll
          for (int j = 0; j < 4; ++j) {
            float v = acc[m][n][j];
            g16[(size_t)(row + j) * 3072 + gcol] = (_Float16)v;
            s[n] += v;
            q[n] += v * v;
          }
        }
      }
#pragma unroll
      for (int n = 0; n < 4; ++n) {
        float sv = s[n], qv = q[n];
        sv += __shfl_xor(sv, 16); sv += __shfl_xor(sv, 32);
        qv += __shfl_xor(qv, 16); qv += __shfl_xor(qv, 32);
        if (lane < 16) {
          int prow = by * 2 + (wid >> 1);            // 64 partial rows
          int pcol = bcol + wcol + n * 16 + lane;
          psum[(size_t)prow * 3072 + pcol] = sv;
          psq [(size_t)prow * 3072 + pcol] = qv;
        }
      }
    } else {                          // raw gh_u (fp16), ghbuf stride 2048
      int gh0 = bcol - 3072;
#pragma unroll
      for (int m = 0; m < 4; ++m) {
        int row = brow + wrow + m * 16 + (lane >> 4) * 4;
#pragma unroll
        for (int n = 0; n < 4; ++n) {
          int gcol = gh0 + wcol + n * 16 + (lane & 15);
#pragma unroll
          for (int j = 0; j < 4; ++j)
            ghbuf[(size_t)(row + j) * 2048 + gcol] = (_Float16)acc[m][n][j];
        }
      }
    }
  } else {
    // ---- phase 2: 128x64, 2-pass (B hi+lo) over gh_r.  XCD = 2 colgrp x
    // 4 rowgrp; bx fast.
    int b2  = bid - 1024;                            // 0..511
    int xcd = b2 & 7;
    int i   = b2 >> 3;                               // 0..63
    int bx  = (xcd & 1) * 8 + (i & 7);               // 0..15
    int by  = (xcd >> 1) * 8 + (i >> 3);             // 0..31
    const int brow = by * 128;
    const int bcol = bx * 64;                        // 0..1023 within r
    const int wrow = (wid >> 1) * 64;
    const int wcol = (wid & 1) * 32;

    const _Float16* Ap = Hf16 + (size_t)brow * 1024;
    const _Float16* Bp = WhTh + (size_t)(1024 + bcol) * 1024;
    const _Float16* Bl = WhTl + (size_t)(1024 + bcol) * 1024;

    f32x4 acc[4][2];
#pragma unroll
    for (int a = 0; a < 4; ++a)
#pragma unroll
      for (int j = 0; j < 2; ++j) acc[a][j] = f32x4{0.f, 0.f, 0.f, 0.f};

    kloop<true, 128, 64, 64>(Ap, Bp, Bl, lds, tid, acc);

#pragma unroll
    for (int m = 0; m < 4; ++m) {
      int row = brow + wrow + m * 16 + (lane >> 4) * 4;
#pragma unroll
      for (int n = 0; n < 2; ++n) {
        int gcol = 1024 + bcol + wcol + n * 16 + (lane & 15);   // gh_r cols
#pragma unroll
        for (int j = 0; j < 4; ++j)
          ghbuf[(size_t)(row + j) * 2048 + gcol] = (_Float16)acc[m][n][j];
      }
    }
  }
}

// ---- GEMM3: ch = rx @ wh_c (64x64 tiles, BK=128, 1024 blocks);
//      epilogue computes u (from raw gh_u) and hy.  XCD = 2 colgrp x 4 rowgrp.
__global__ __launch_bounds__(256, 4) void gemm_last(
    const _Float16* __restrict__ RXf16, const _Float16* __restrict__ Bc,
    const _Float16* __restrict__ g16, const _Float16* __restrict__ ghbuf,
    const _Float16* __restrict__ Hf16, const float* __restrict__ scale,
    const float* __restrict__ shift, float* __restrict__ out) {
  __shared__ _Float16 lds[64 * 128 + 64 * 128];      // 32 KiB

  const int tid  = threadIdx.x;
  const int lane = tid & 63;
  const int wid  = tid >> 6;

  int bid = blockIdx.x;                              // 0..1023
  int xcd = bid & 7;
  int i   = bid >> 3;                                // 0..127
  int bx  = (xcd & 1) * 8 + (i & 7);                 // 0..15
  int by  = (xcd >> 1) * 16 + (i >> 3);              // 0..63

  const int brow = by * 64;
  const int bcol = bx * 64;                          // 0..1023
  const int wrow = (wid >> 1) * 32;
  const int wcol = (wid & 1) * 32;

  f32x4 acc[2][2];
#pragma unroll
  for (int a = 0; a < 2; ++a)
#pragma unroll
    for (int j = 0; j < 2; ++j) acc[a][j] = f32x4{0.f, 0.f, 0.f, 0.f};

  kloop<false, 64, 64, 128>(RXf16 + (size_t)brow * 1024,
                            Bc + (size_t)bcol * 1024, nullptr, lds, tid, acc);

#pragma unroll
  for (int m = 0; m < 2; ++m) {
    int row0 = brow + wrow + m * 16 + (lane >> 4) * 4;
#pragma unroll
    for (int n = 0; n < 2; ++n) {
      int lcol = bcol + wcol + n * 16 + (lane & 15);
      float sc_u = scale[lcol],        sf_u = shift[lcol];
      float sc_c = scale[2048 + lcol], sf_c = shift[2048 + lcol];
#pragma unroll
      for (int j = 0; j < 4; ++j) {
        int row = row0 + j;
        float gu = (float)g16[(size_t)row * 3072 + lcol];
        float hu = (float)ghbuf[(size_t)row * 2048 + lcol];
        float u  = sigm(gu * sc_u + sf_u + hu);
        float gc = (float)g16[(size_t)row * 3072 + 2048 + lcol];
        float c  = tanh_sat(gc * sc_c + sf_c + acc[m][n][j]);
        float x  = (float)Hf16[(size_t)row * 1024 + lcol];
        out[(size_t)row * 1024 + lcol] = x + u * (c - x);
      }
    }
  }
}

// --------------------------- BN final ---------------------------------------

__global__ void bn_final(const float* __restrict__ psum, const float* __restrict__ psq,
                         const float* __restrict__ gamma, const float* __restrict__ beta,
                         const float* __restrict__ bias, float* __restrict__ scale,
                         float* __restrict__ shift, int nparts, int Ncols, float invM) {
  int col = blockIdx.x * blockDim.x + threadIdx.x;
  if (col >= Ncols) return;
  float s = 0.f, q = 0.f;
  for (int i = 0; i < nparts; ++i) {
    s += psum[(size_t)i * Ncols + col];
    q += psq [(size_t)i * Ncols + col];
  }
  float m   = s * invM;
  float var = q * invM - m * m;
  float r   = rsqrtf(var + 1e-5f);
  float sc  = r * gamma[col];
  scale[col] = sc;
  shift[col] = beta[col] + bias[col] - m * sc;
}

// --------------------- rx = sigmoid(BN(g_r)+gh_r) * hx ----------------------

__global__ void rx_split(const _Float16* __restrict__ g16,
                         const _Float16* __restrict__ ghbuf,
                         const _Float16* __restrict__ Hf16,
                         const float* __restrict__ scale,
                         const float* __restrict__ shift,
                         _Float16* __restrict__ rx) {
  int idx = blockIdx.x * blockDim.x + threadIdx.x;   // 4096*256
  int row = idx >> 8;
  int cv  = idx & 255;
  half4 gr = ((const half4*)g16)[(size_t)row * 768 + 256 + cv];   // g cols 1024+
  half4 hr = ((const half4*)ghbuf)[(size_t)row * 512 + 256 + cv]; // gh cols 1024+
  half4 xv = ((const half4*)Hf16)[(size_t)row * 256 + cv];
  int col = 1024 + cv * 4;
  f4 sr = *(const f4*)&scale[col];
  f4 fr = *(const f4*)&shift[col];
  half4 o;
#pragma unroll
  for (int j = 0; j < 4; ++j) {
    float r = sigm((float)gr[j] * sr[j] + fr[j] + (float)hr[j]);
    o[j] = (_Float16)(r * (float)xv[j]);
  }
  ((half4*)rx)[(size_t)row * 256 + cv] = o;
}

// ------------------------------ launch ---------------------------------------

extern "C" void kernel_launch(void* const* d_in, const int* in_sizes, int n_in,
                              void* d_out, int out_size, void* d_ws, size_t ws_size,
                              hipStream_t stream) {
  const float* input = (const float*)d_in[0];   // 4096x1024
  const float* hx    = (const float*)d_in[1];   // 4096x1024
  const float* wi    = (const float*)d_in[2];   // 1024x3072
  const float* wh    = (const float*)d_in[3];   // 1024x3072
  const float* bias  = (const float*)d_in[4];   // 3072
  const float* gamma = (const float*)d_in[5];   // 3072
  const float* beta  = (const float*)d_in[6];   // 3072
  float* out = (float*)d_out;

  const int B = 4096, N3 = 3072;

  char* ws = (char*)d_ws;
  _Float16* g16   = (_Float16*)(ws);               // 24 MiB [4096][3072]
  _Float16* ghbuf = (_Float16*)(ws + 25165824);    // 16 MiB [4096][2048] raw
  _Float16* Xf16  = (_Float16*)(ws + 41943040);    // 8 MiB
  _Float16* Hf16  = (_Float16*)(ws + 50331648);    // 8 MiB
  _Float16* RXf16 = (_Float16*)(ws + 58720256);    // 8 MiB
  _Float16* WiT   = (_Float16*)(ws + 67108864);    // 6 MiB
  _Float16* WhTh  = (_Float16*)(ws + 73400320);    // 6 MiB
  _Float16* WhTl  = (_Float16*)(ws + 79691776);    // 6 MiB (r-cols only)
  float*    psum  = (float*)   (ws + 85983232);    // 768 KiB [64][3072]
  float*    psq   = (float*)   (ws + 86769664);    // 768 KiB
  float*    scale = (float*)   (ws + 87556096);    // 12 KiB
  float*    shift = (float*)   (ws + 87568384);    // 12 KiB

  // ---- prep: converts + transposes, one dispatch
  prep_all<<<8192 + 6144, 256, 0, stream>>>(input, hx, wi, wh,
                                            Xf16, Hf16, WiT, WhTh, WhTl);

  // ---- MEGA GEMM: [g | gh_u] 128x128 1-pass + gh_r 128x64 2-pass
  gemm_mega<<<1536, 256, 0, stream>>>(
      Xf16, Hf16, WiT, WhTh, WhTl, g16, ghbuf, psum, psq);

  // ---- BN fold
  bn_final<<<12, 256, 0, stream>>>(psum, psq, gamma, beta, bias,
                                   scale, shift, 64, N3, 1.f / (float)B);

  // ---- rx = sigmoid(BN(g_r) + gh_r) * hx
  rx_split<<<4096, 256, 0, stream>>>(g16, ghbuf, Hf16, scale, shift, RXf16);

  // ---- GEMM3 + fused u/c/hy epilogue (64x64, BK=128, 1024 blocks)
  gemm_last<<<1024, 256, 0, stream>>>(
      RXf16, WhTh + (size_t)2048 * 1024, g16, ghbuf, Hf16, scale, shift, out);
}